// Round 10
// baseline (314.792 us; speedup 1.0000x reference)
//
#include <hip/hip_runtime.h>
#include <math.h>

// NoisyTopKGating: out[N,64] = scatter(softmax(top2(x@W^T + b + noise)))
// N=131072, D=1024, E=64, K=2, NOISE_STD=1.0
//
// Round 10: 1KB-run staging (KCF=256). Measured trend R4-R9: effective x BW
// rises monotonically with DRAM run length (64B:2.3, 128B:2.6, 512B:2.9 TB/s;
// contiguous fills: 6.7). This round stages a QUARTER ROW (1 KB contiguous)
// per row per visit: chunk = 64 rows x 1KB = 64KB, NBUF=2 (128KB LDS, 1
// block/CU, gfx950 allows 160KB/WG). W now loaded per-kstep from the
// L2-resident frag-major image (saves 64 VGPR; vmcnt algebra: stage(c+1)'s
// 16 DMAs are always the newest 16 -> vmcnt(16) == stage(c)+W(c-1) landed,
// never 0 in-loop). Per-block k-phase rotation kept. Epilogue identical to
// R9 (proven). logits = xh*wh + xh*wl + xl*wh (err ~4e-6 << TAU); fp64
// repair pass for rows with gap(#2,#3) < TAU (proven rounds 3-9).

#define NEXP   64
#define BLOCK  256
#define TILE_M 64
#define DFIX   1024
#define KCF    256       // K floats per chunk -> 1024 B per row per visit
#define NCH    4         // DFIX / KCF
#define XCHB   65536     // x chunk: 64 rows x 1024 B
#define TAU    1e-3f
#define CAP    4096
#define WS_W_OFF 32768   // frag-major W image at d_ws + 32 KB

typedef __attribute__((ext_vector_type(8)))  short bf16x8;
typedef __attribute__((ext_vector_type(16))) float f32x16;

__device__ __forceinline__ bool beats(float v, int e, float vo, int eo) {
    // jax.lax.top_k ordering: higher value wins, lower index on tie
    return (v > vo) || (v == vo && e < eo);
}

// Split two fp32 into packed bf16-hi pair and bf16-lo (residual) pair, by truncation.
__device__ __forceinline__ void split2(float f0, float f1, unsigned int& hi, unsigned int& lo) {
    unsigned int u0 = __float_as_uint(f0), u1 = __float_as_uint(f1);
    unsigned int h0 = u0 & 0xFFFF0000u,  h1 = u1 & 0xFFFF0000u;
    float l0 = f0 - __uint_as_float(h0);
    float l1 = f1 - __uint_as_float(h1);
    hi = (u0 >> 16) | h1;
    lo = (__float_as_uint(l0) >> 16) | (__float_as_uint(l1) & 0xFFFF0000u);
}

__device__ __forceinline__ void gl_lds16(const void* g, void* l) {
    __builtin_amdgcn_global_load_lds((const __attribute__((address_space(1))) void*)g,
                                     (__attribute__((address_space(3))) void*)l,
                                     16, 0, 0);
}

// W (64x1024 fp32) -> frag-major bf16 hi/lo image (256 KB):
// frag f = kk*4 + g*2 + h (kk = k-step 0..63, g = expert-half, h: 0=hi 1=lo),
// lane l of frag f holds W[e = g*32 + (l&31)][k = kk*16 + (l>>5)*8 .. +8] (16B).
__global__ void convW_kernel(const float* __restrict__ W, char* __restrict__ wsW) {
    const int e = blockIdx.x;        // 0..63
    const int t = threadIdx.x;       // 0..127 = global k-octet
    const float* wp = W + e * DFIX + t * 8;
    float4 a  = *(const float4*)wp;
    float4 bq = *(const float4*)(wp + 4);
    unsigned int h[4], l[4];
    split2(a.x,  a.y,  h[0], l[0]);
    split2(a.z,  a.w,  h[1], l[1]);
    split2(bq.x, bq.y, h[2], l[2]);
    split2(bq.z, bq.w, h[3], l[3]);
    const int kk   = t >> 1;         // k-step 0..63
    const int lh   = t & 1;          // k-octet within k-step
    const int lane = lh * 32 + (e & 31);
    const int g    = e >> 5;
    char* base = wsW + (size_t)(kk * 4 + g * 2) * 1024 + lane * 16;
    *(uint4*)(base)        = make_uint4(h[0], h[1], h[2], h[3]);  // h=0 (hi)
    *(uint4*)(base + 1024) = make_uint4(l[0], l[1], l[2], l[3]);  // h=1 (lo)
}

__global__ __launch_bounds__(BLOCK, 1)
void gate_mfma(const float* __restrict__ x, const float* __restrict__ bvec,
               const float* __restrict__ noise, const char* __restrict__ wsW,
               float* __restrict__ out, unsigned int* __restrict__ flags) {
    __shared__ __align__(16) char lds[2 * XCHB];   // 128 KB -> 1 block/CU

    const int tid  = threadIdx.x;
    const int wv   = tid >> 6;       // wave 0..3
    const int lane = tid & 63;
    const int e0   = lane & 31;
    const int lh   = lane >> 5;      // k-octet half selector
    const int rg   = wv & 1;         // row group: rows rg*32..+32
    const int cg   = wv >> 1;        // col group: experts cg*32..+32
    const int blkRow0 = blockIdx.x * TILE_M;
    const int rowL  = rg * 32 + e0;  // this lane's A row within tile (0..63)
    const int phase = blockIdx.x & (NCH - 1);   // k-phase rotation (R7)

    f32x16 acc = (f32x16)0.0f;       // 32 rows x 32 experts per wave

    // Stage GLOBAL chunk gc (1KB per row) into buffer buf: 16 gl_lds16/wave,
    // each instruction = ONE row's full 1KB segment (64 lanes x 16B contiguous,
    // lane-permuted by seg = lane ^ row; inverse-swizzled source, linear dest).
    auto STAGE = [&](int gc, int buf) {
        char* xb = lds + buf * XCHB;
        #pragma unroll
        for (int i = 0; i < 16; i++) {
            const int row = wv * 16 + i;                // 0..63
            const int seg = lane ^ row;                 // permute within the 1KB run
            const char* gp = (const char*)(x + (size_t)(blkRow0 + row) * DFIX)
                             + (size_t)gc * 1024 + seg * 16;
            gl_lds16(gp, xb + (size_t)(wv * 1024 + i * 64) * 16);  // +lane*16 by HW
        }
    };

    // COMPUTE chunk gc from buffer buf. W frags loaded per-kstep from the
    // L2-resident image (compiler inserts its own waits; DMA builtins are
    // modeled so its vmcnt counts stay exact).
    auto COMPUTE = [&](int gc, int buf) {
        const char* xb = lds + buf * XCHB;
        #pragma unroll
        for (int ks = 0; ks < 16; ks++) {
            const int kkg = gc * 16 + ks;               // global k-step 0..63
            const char* wbase = wsW + (size_t)(kkg * 4 + cg * 2) * 1024 + lane * 16;
            union { bf16x8 v; int4 q; } bh, bl;
            bh.q = *(const int4*)(wbase);
            bl.q = *(const int4*)(wbase + 1024);
            const int g0 = ks * 4 + lh * 2;             // global seg wanted
            const int4 xq0 = *(const int4*)(xb + rowL * 1024 + ((g0    ) ^ rowL) * 16);
            const int4 xq1 = *(const int4*)(xb + rowL * 1024 + ((g0 + 1) ^ rowL) * 16);
            const float4 xa = *(const float4*)&xq0;
            const float4 xc = *(const float4*)&xq1;
            union { bf16x8 v; unsigned int u[4]; } ah, al;
            split2(xa.x, xa.y, ah.u[0], al.u[0]);
            split2(xa.z, xa.w, ah.u[1], al.u[1]);
            split2(xc.x, xc.y, ah.u[2], al.u[2]);
            split2(xc.z, xc.w, ah.u[3], al.u[3]);
            acc = __builtin_amdgcn_mfma_f32_32x32x16_bf16(ah.v, bh.v, acc, 0, 0, 0);
            acc = __builtin_amdgcn_mfma_f32_32x32x16_bf16(ah.v, bl.v, acc, 0, 0, 0);
            acc = __builtin_amdgcn_mfma_f32_32x32x16_bf16(al.v, bh.v, acc, 0, 0, 0);
        }
    };

    // Pipeline: NBUF=2, dual barrier per chunk; counted vmcnt never 0 in-loop.
    // At vmcnt(16): newest 16 outstanding = stage(c+1) -> stage(c) + W(c-1) done.
    STAGE(phase, 0);
    #pragma unroll 1
    for (int c = 0; c < NCH - 1; c++) {
        STAGE((c + 1 + phase) & (NCH - 1), (c + 1) & 1);
        asm volatile("s_waitcnt vmcnt(16)" ::: "memory");
        __builtin_amdgcn_s_barrier();
        __builtin_amdgcn_sched_barrier(0);
        COMPUTE((c + phase) & (NCH - 1), c & 1);
        __builtin_amdgcn_s_barrier();   // all waves done reading buf (c&1)
    }
    asm volatile("s_waitcnt vmcnt(0)" ::: "memory");
    __builtin_amdgcn_s_barrier();
    __builtin_amdgcn_sched_barrier(0);
    COMPUTE((NCH - 1 + phase) & (NCH - 1), (NCH - 1) & 1);

    // ---- Epilogue (identical to R9, proven): logits -> LDS (swizzled 16B
    // slots in buf0 region, disjoint from buf1 read by final COMPUTE),
    // __syncthreads, thread-quad top-k + 2-step shuffle merge, scatter. ----
    // C layout (verified m74/m101 + rounds 3-9): col = lane&31,
    // row = (reg&3) + 8*(reg>>2) + 4*lh.
    const float bb = bvec[cg * 32 + e0];
    #pragma unroll
    for (int q = 0; q < 4; q++) {
        #pragma unroll
        for (int j = 0; j < 4; j++) {
            const int reg = q * 4 + j;
            const int rl  = rg * 32 + j + 8 * q + 4 * lh;   // row local 0..63
            const int r   = blkRow0 + rl;
            const int col = cg * 32 + e0;
            const float v = (acc[reg] + bb) + noise[(size_t)r * NEXP + col];
            const int slot = (col >> 2) ^ (rl & 15);        // bank-spread swizzle
            *(float*)(lds + rl * 256 + slot * 16 + (col & 3) * 4) = v;
        }
    }
    __syncthreads();   // ds_write -> cross-wave ds_read handoff (R8 lesson)

    {
        const int trow = tid >> 2;
        const int qd   = tid & 3;
        float v1 = -1e30f, v2 = -1e30f, v3 = -1e30f;
        int   e1 = 99, e2 = 99;
        #pragma unroll
        for (int i = 0; i < 4; i++) {
            const int slot = (qd * 4 + i) ^ (trow & 15);
            const float4 f = *(const float4*)(lds + trow * 256 + slot * 16);
            #pragma unroll
            for (int m = 0; m < 4; m++) {
                const float v = (m == 0) ? f.x : (m == 1) ? f.y : (m == 2) ? f.z : f.w;
                const int   e = qd * 16 + i * 4 + m;
                if (beats(v, e, v1, e1))      { v3 = v2; v2 = v1; e2 = e1; v1 = v; e1 = e; }
                else if (beats(v, e, v2, e2)) { v3 = v2; v2 = v;  e2 = e; }
                else                          { v3 = fmaxf(v3, v); }
            }
        }
        #pragma unroll
        for (int d = 1; d < 4; d <<= 1) {
            float ov1 = __shfl_xor(v1, d); int oe1 = __shfl_xor(e1, d);
            float ov2 = __shfl_xor(v2, d); int oe2 = __shfl_xor(e2, d);
            float ov3 = __shfl_xor(v3, d);
            bool  aw  = beats(v1, e1, ov1, oe1);
            float a1v = aw ? v1 : ov1; int a1e = aw ? e1 : oe1;
            float b1v = aw ? ov1 : v1; int b1e = aw ? oe1 : e1;
            float a2v = aw ? v2 : ov2; int a2e = aw ? e2 : oe2;
            float b2v = aw ? ov2 : v2;
            float a3v = aw ? v3 : ov3;
            bool  s2  = beats(a2v, a2e, b1v, b1e);
            v1 = a1v; e1 = a1e;
            v2 = s2 ? a2v : b1v; e2 = s2 ? a2e : b1e;
            v3 = s2 ? fmaxf(a3v, b1v) : fmaxf(a2v, b2v);
        }
        const float t   = __expf(v2 - v1);
        const float inv = 1.0f / (1.0f + t);
        const float w1  = inv, w2 = t * inv;
        const int   r   = blkRow0 + trow;

        if (qd == 0 && (v2 - v3) < TAU) {
            unsigned int idx = atomicAdd(flags, 1u);
            if (idx < CAP) flags[1 + idx] = (unsigned int)r;
        }
        float* op = out + (size_t)r * NEXP + qd * 16;
        #pragma unroll
        for (int i = 0; i < 4; i++) {
            float o[4];
            #pragma unroll
            for (int m = 0; m < 4; m++) {
                const int e = qd * 16 + i * 4 + m;
                o[m] = (e == e1) ? w1 : (e == e2) ? w2 : 0.0f;
            }
            *(float4*)(op + i * 4) = make_float4(o[0], o[1], o[2], o[3]);
        }
    }
}

// fp64 re-solve of flagged rows: one 64-lane block per row, lane = expert.
__global__ void gate_repair(const float* __restrict__ x, const float* __restrict__ W,
                            const float* __restrict__ b, const float* __restrict__ noise,
                            float* __restrict__ out, const unsigned int* __restrict__ flags,
                            int D) {
    unsigned int cnt = flags[0];
    if (cnt > CAP) cnt = CAP;
    if (blockIdx.x >= cnt) return;
    const int r = (int)flags[1 + blockIdx.x];
    const int e = threadIdx.x;  // 0..63

    const float* xr = x + (size_t)r * D;
    const float* wr = W + (size_t)e * D;
    double s = 0.0;
    for (int d0 = 0; d0 < D; d0 += 4) {
        float4 xv = *(const float4*)(xr + d0);
        float4 wv = *(const float4*)(wr + d0);
        s += (double)xv.x * (double)wv.x;
        s += (double)xv.y * (double)wv.y;
        s += (double)xv.z * (double)wv.z;
        s += (double)xv.w * (double)wv.w;
    }
    const float clean = (float)s + b[e];
    const float v     = clean + noise[(size_t)r * NEXP + e];

    float v1 = v, v2 = -1e30f; int e1 = e, e2 = 99;
    for (int d = 1; d < 64; d <<= 1) {
        float ov1 = __shfl_xor(v1, d); int oe1 = __shfl_xor(e1, d);
        float ov2 = __shfl_xor(v2, d); int oe2 = __shfl_xor(e2, d);
        bool  aw  = beats(v1, e1, ov1, oe1);
        float a1v = aw ? v1 : ov1; int a1e = aw ? e1 : oe1;
        float b1v = aw ? ov1 : v1; int b1e = aw ? oe1 : e1;
        float a2v = aw ? v2 : ov2; int a2e = aw ? e2 : oe2;
        bool  s2  = beats(a2v, a2e, b1v, b1e);
        v1 = a1v; e1 = a1e;
        v2 = s2 ? a2v : b1v; e2 = s2 ? a2e : b1e;
    }
    const float t   = __expf(v2 - v1);
    const float inv = 1.0f / (1.0f + t);
    out[(size_t)r * NEXP + e] = (e == e1) ? inv : (e == e2) ? t * inv : 0.0f;
}

extern "C" void kernel_launch(void* const* d_in, const int* in_sizes, int n_in,
                              void* d_out, int out_size, void* d_ws, size_t ws_size,
                              hipStream_t stream) {
    const float* x     = (const float*)d_in[0];
    const float* W     = (const float*)d_in[1];
    const float* b     = (const float*)d_in[2];
    const float* noise = (const float*)d_in[3];
    float* out = (float*)d_out;

    const int E = in_sizes[2];       // 64
    const int D = in_sizes[1] / E;   // 1024
    const int N = in_sizes[0] / D;   // 131072

    unsigned int* flags = (unsigned int*)d_ws;
    char* wsW = (char*)d_ws + WS_W_OFF;

    convW_kernel<<<dim3(E), dim3(128), 0, stream>>>(W, wsW);
    hipMemsetAsync(d_ws, 0, sizeof(unsigned int), stream);
    gate_mfma<<<dim3(N / TILE_M), dim3(BLOCK), 0, stream>>>(x, b, noise, wsW, out, flags);
    gate_repair<<<dim3(CAP), dim3(64), 0, stream>>>(x, W, b, noise, out, flags, D);
}

// Round 11
// 229.442 us; speedup vs baseline: 1.3720x; 1.3720x over previous
//
#include <hip/hip_runtime.h>
#include <math.h>

// NoisyTopKGating: out[N,64] = scatter(softmax(top2(x@W^T + b + noise)))
// N=131072, D=1024, E=64, K=2, NOISE_STD=1.0
//
// Round 11: 1KB runs AT 2 blocks/CU (R10 retried without the occupancy cut).
// TILE_M=32: chunk = 32 rows x 1KB = 32KB, NBUF=2 = 64KB LDS -> 2 blocks/CU.
// Waves = (cg expert-half, kh kstep-half): each computes a partial 32x32 acc
// over its 8/16 ksteps per chunk; partials combined once via LDS at the end.
// W via R9-proven register preload (WPRE), sched_barrier(0) fences pin the
// WPRE->STAGE issue order so counted vmcnt(8) is exact (never 0 in-loop).
// Per-block k-phase rotation kept. Octet (8-thread/row) top-k epilogue (R3-
// proven merge). logits = xh*wh + xh*wl + xl*wh (err ~4e-6 << TAU); fp64
// repair pass for rows with gap(#2,#3) < TAU (proven rounds 3-10).

#define NEXP   64
#define BLOCK  256
#define TILE_M 32
#define DFIX   1024
#define NCH    4         // 4 chunks x 1KB per row
#define XCHB   32768     // 32 rows x 1KB
#define TK_OFF 8192      // logits region within buf0 (combine uses 0..8KB)
#define TAU    1e-3f
#define CAP    4096
#define WS_W_OFF 32768   // frag-major W image at d_ws + 32 KB

typedef __attribute__((ext_vector_type(8)))  short bf16x8;
typedef __attribute__((ext_vector_type(16))) float f32x16;

__device__ __forceinline__ bool beats(float v, int e, float vo, int eo) {
    // jax.lax.top_k ordering: higher value wins, lower index on tie
    return (v > vo) || (v == vo && e < eo);
}

// Split two fp32 into packed bf16-hi pair and bf16-lo (residual) pair, by truncation.
__device__ __forceinline__ void split2(float f0, float f1, unsigned int& hi, unsigned int& lo) {
    unsigned int u0 = __float_as_uint(f0), u1 = __float_as_uint(f1);
    unsigned int h0 = u0 & 0xFFFF0000u,  h1 = u1 & 0xFFFF0000u;
    float l0 = f0 - __uint_as_float(h0);
    float l1 = f1 - __uint_as_float(h1);
    hi = (u0 >> 16) | h1;
    lo = (__float_as_uint(l0) >> 16) | (__float_as_uint(l1) & 0xFFFF0000u);
}

__device__ __forceinline__ void gl_lds16(const void* g, void* l) {
    __builtin_amdgcn_global_load_lds((const __attribute__((address_space(1))) void*)g,
                                     (__attribute__((address_space(3))) void*)l,
                                     16, 0, 0);
}

// W (64x1024 fp32) -> frag-major bf16 hi/lo image (256 KB):
// frag f = kk*4 + g*2 + h (kk = k-step 0..63, g = expert-half, h: 0=hi 1=lo),
// lane l of frag f holds W[e = g*32 + (l&31)][k = kk*16 + (l>>5)*8 .. +8] (16B).
__global__ void convW_kernel(const float* __restrict__ W, char* __restrict__ wsW) {
    const int e = blockIdx.x;        // 0..63
    const int t = threadIdx.x;       // 0..127 = global k-octet
    const float* wp = W + e * DFIX + t * 8;
    float4 a  = *(const float4*)wp;
    float4 bq = *(const float4*)(wp + 4);
    unsigned int h[4], l[4];
    split2(a.x,  a.y,  h[0], l[0]);
    split2(a.z,  a.w,  h[1], l[1]);
    split2(bq.x, bq.y, h[2], l[2]);
    split2(bq.z, bq.w, h[3], l[3]);
    const int kk   = t >> 1;         // k-step 0..63
    const int lh   = t & 1;          // k-octet within k-step
    const int lane = lh * 32 + (e & 31);
    const int g    = e >> 5;
    char* base = wsW + (size_t)(kk * 4 + g * 2) * 1024 + lane * 16;
    *(uint4*)(base)        = make_uint4(h[0], h[1], h[2], h[3]);  // h=0 (hi)
    *(uint4*)(base + 1024) = make_uint4(l[0], l[1], l[2], l[3]);  // h=1 (lo)
}

__global__ __launch_bounds__(BLOCK, 2)
void gate_mfma(const float* __restrict__ x, const float* __restrict__ bvec,
               const float* __restrict__ noise, const char* __restrict__ wsW,
               float* __restrict__ out, unsigned int* __restrict__ flags) {
    __shared__ __align__(16) char lds[2 * XCHB];   // 64 KB -> 2 blocks/CU

    const int tid  = threadIdx.x;
    const int wv   = tid >> 6;       // wave 0..3
    const int lane = tid & 63;
    const int e0   = lane & 31;      // A-row / expert col within half
    const int lh   = lane >> 5;      // k-octet half selector
    const int cg   = wv & 1;         // expert half: experts cg*32..+32
    const int kh   = wv >> 1;        // kstep half within each chunk
    const int blkRow0 = blockIdx.x * TILE_M;
    const int rowL  = e0;            // this lane's A row within tile (0..31)
    const int phase = blockIdx.x & (NCH - 1);   // k-phase rotation (R7)

    f32x16 acc = (f32x16)0.0f;       // partial: 32 rows x 32 experts, kh's ksteps

    // Stage GLOBAL chunk gc (1KB per row, 32 rows) into buffer buf:
    // 8 gl_lds16 per wave, each = ONE row's full 1KB contiguous run
    // (64 lanes x 16B, lane-permuted seg = lane ^ row; linear LDS dest).
    auto STAGE = [&](int gc, int buf) {
        char* xb = lds + buf * XCHB;
        #pragma unroll
        for (int i = 0; i < 8; i++) {
            const int row = wv * 8 + i;                 // 0..31
            const int seg = lane ^ row;                 // involution, both sides
            const char* gp = (const char*)(x + (size_t)(blkRow0 + row) * DFIX)
                             + (size_t)gc * 1024 + seg * 16;
            gl_lds16(gp, xb + (size_t)(row * 64) * 16); // +lane*16 by HW
        }
    };

    // This wave's W frags for chunk gc: its kh-half (8 ksteps) x hi/lo -> regs.
    int4 wreg[16];
    auto WPRE = [&](int gc) {
        const int kk0 = gc * 16 + kh * 8;
        const char* base = wsW + (size_t)(kk0 * 4 + cg * 2) * 1024 + lane * 16;
        #pragma unroll
        for (int ks = 0; ks < 8; ks++) {
            wreg[ks * 2 + 0] = *(const int4*)(base + (size_t)(ks * 4) * 1024);         // hi
            wreg[ks * 2 + 1] = *(const int4*)(base + (size_t)(ks * 4) * 1024 + 1024);  // lo
        }
    };

    auto COMPUTE = [&](int buf) {
        const char* xb = lds + buf * XCHB;
        #pragma unroll
        for (int ks = 0; ks < 8; ks++) {
            const int ksc = kh * 8 + ks;                // kstep within chunk 0..15
            const int g0  = ksc * 4 + lh * 2;           // seg within the 1KB run
            const int4 xq0 = *(const int4*)(xb + rowL * 1024 + ((g0    ) ^ rowL) * 16);
            const int4 xq1 = *(const int4*)(xb + rowL * 1024 + ((g0 + 1) ^ rowL) * 16);
            const float4 xa = *(const float4*)&xq0;
            const float4 xc = *(const float4*)&xq1;
            union { bf16x8 v; unsigned int u[4]; } ah, al;
            split2(xa.x, xa.y, ah.u[0], al.u[0]);
            split2(xa.z, xa.w, ah.u[1], al.u[1]);
            split2(xc.x, xc.y, ah.u[2], al.u[2]);
            split2(xc.z, xc.w, ah.u[3], al.u[3]);
            union { bf16x8 v; int4 q; } bh, bl;
            bh.q = wreg[ks * 2 + 0];
            bl.q = wreg[ks * 2 + 1];
            acc = __builtin_amdgcn_mfma_f32_32x32x16_bf16(ah.v, bh.v, acc, 0, 0, 0);
            acc = __builtin_amdgcn_mfma_f32_32x32x16_bf16(ah.v, bl.v, acc, 0, 0, 0);
            acc = __builtin_amdgcn_mfma_f32_32x32x16_bf16(al.v, bh.v, acc, 0, 0, 0);
        }
    };

    // Pipeline: NBUF=2, dual barrier; counted vmcnt never 0 in-loop.
    // Issue order pinned by sched_barrier(0): WPRE(c)[16] then STAGE(c+1)[8]
    // -> at vmcnt(8) the newest 8 = stage(c+1), so stage(c)+WPRE(c) landed.
    STAGE(phase, 0);
    #pragma unroll 1
    for (int c = 0; c < NCH - 1; c++) {
        WPRE((c + phase) & (NCH - 1));
        __builtin_amdgcn_sched_barrier(0);
        STAGE((c + 1 + phase) & (NCH - 1), (c + 1) & 1);
        __builtin_amdgcn_sched_barrier(0);
        asm volatile("s_waitcnt vmcnt(8)" ::: "memory");
        __builtin_amdgcn_s_barrier();
        __builtin_amdgcn_sched_barrier(0);
        COMPUTE(c & 1);
        __builtin_amdgcn_s_barrier();   // all waves done reading buf (c&1)
    }
    WPRE((NCH - 1 + phase) & (NCH - 1));
    asm volatile("s_waitcnt vmcnt(0)" ::: "memory");
    __builtin_amdgcn_s_barrier();
    __builtin_amdgcn_sched_barrier(0);
    COMPUTE((NCH - 1) & 1);            // reads buf1; buf0 free for epilogue

    // ---- Combine kh partials via LDS (buf0 region, disjoint from buf1) ----
    __syncthreads();                   // everyone done with buf1 reads
    union { f32x16 v; float4 f4[4]; } au; au.v = acc;
    if (kh == 1) {
        #pragma unroll
        for (int r4 = 0; r4 < 4; r4++)
            *(float4*)(lds + cg * 4096 + r4 * 1024 + lane * 16) = au.f4[r4];
    }
    __syncthreads();
    if (kh == 0) {
        #pragma unroll
        for (int r4 = 0; r4 < 4; r4++) {
            const float4 t = *(const float4*)(lds + cg * 4096 + r4 * 1024 + lane * 16);
            au.f4[r4].x += t.x; au.f4[r4].y += t.y; au.f4[r4].z += t.z; au.f4[r4].w += t.w;
        }
        // logits + bias + noise -> swizzled TK region.
        // C layout (verified m74/m101 + rounds 3-10): col = lane&31,
        // row = (reg&3) + 8*(reg>>2) + 4*lh.
        const float bb = bvec[cg * 32 + e0];
        #pragma unroll
        for (int q = 0; q < 4; q++) {
            #pragma unroll
            for (int j = 0; j < 4; j++) {
                const int reg = q * 4 + j;
                const int rl  = j + 8 * q + 4 * lh;     // row local 0..31
                const int r   = blkRow0 + rl;
                const int col = cg * 32 + e0;
                const float v = (au.f4[reg >> 2].x * 0.0f) +  // (keep indexing simple below)
                                ((reg & 3) == 0 ? au.f4[reg >> 2].x :
                                 (reg & 3) == 1 ? au.f4[reg >> 2].y :
                                 (reg & 3) == 2 ? au.f4[reg >> 2].z : au.f4[reg >> 2].w)
                                + bb + noise[(size_t)r * NEXP + col];
                const int slot = (col >> 2) ^ (rl & 15);
                *(float*)(lds + TK_OFF + rl * 256 + slot * 16 + (col & 3) * 4) = v;
            }
        }
    }
    __syncthreads();   // ds_write -> cross-wave ds_read handoff (R8 lesson)

    // Octet top-k: tid>>3 = row (0..31), tid&7 = 8-expert span; local top-3,
    // then 3-step xor-shuffle merge (proven in R3's epilogue).
    {
        const int trow = tid >> 3;
        const int oct  = tid & 7;
        float v1 = -1e30f, v2 = -1e30f, v3 = -1e30f;
        int   e1 = 99, e2 = 99;
        #pragma unroll
        for (int i = 0; i < 2; i++) {
            const int slot = (oct * 2 + i) ^ (trow & 15);
            const float4 f = *(const float4*)(lds + TK_OFF + trow * 256 + slot * 16);
            #pragma unroll
            for (int m = 0; m < 4; m++) {
                const float v = (m == 0) ? f.x : (m == 1) ? f.y : (m == 2) ? f.z : f.w;
                const int   e = oct * 8 + i * 4 + m;
                if (beats(v, e, v1, e1))      { v3 = v2; v2 = v1; e2 = e1; v1 = v; e1 = e; }
                else if (beats(v, e, v2, e2)) { v3 = v2; v2 = v;  e2 = e; }
                else                          { v3 = fmaxf(v3, v); }
            }
        }
        #pragma unroll
        for (int d = 1; d < 8; d <<= 1) {
            float ov1 = __shfl_xor(v1, d); int oe1 = __shfl_xor(e1, d);
            float ov2 = __shfl_xor(v2, d); int oe2 = __shfl_xor(e2, d);
            float ov3 = __shfl_xor(v3, d);
            bool  aw  = beats(v1, e1, ov1, oe1);
            float a1v = aw ? v1 : ov1; int a1e = aw ? e1 : oe1;
            float b1v = aw ? ov1 : v1; int b1e = aw ? oe1 : e1;
            float a2v = aw ? v2 : ov2; int a2e = aw ? e2 : oe2;
            float b2v = aw ? ov2 : v2;
            float a3v = aw ? v3 : ov3;
            bool  s2  = beats(a2v, a2e, b1v, b1e);
            v1 = a1v; e1 = a1e;
            v2 = s2 ? a2v : b1v; e2 = s2 ? a2e : b1e;
            v3 = s2 ? fmaxf(a3v, b1v) : fmaxf(a2v, b2v);
        }
        const float t   = __expf(v2 - v1);
        const float inv = 1.0f / (1.0f + t);
        const float w1  = inv, w2 = t * inv;
        const int   r   = blkRow0 + trow;

        if (oct == 0 && (v2 - v3) < TAU) {
            unsigned int idx = atomicAdd(flags, 1u);
            if (idx < CAP) flags[1 + idx] = (unsigned int)r;
        }
        float* op = out + (size_t)r * NEXP + oct * 8;
        #pragma unroll
        for (int i = 0; i < 2; i++) {
            float o[4];
            #pragma unroll
            for (int m = 0; m < 4; m++) {
                const int e = oct * 8 + i * 4 + m;
                o[m] = (e == e1) ? w1 : (e == e2) ? w2 : 0.0f;
            }
            *(float4*)(op + i * 4) = make_float4(o[0], o[1], o[2], o[3]);
        }
    }
}

// fp64 re-solve of flagged rows: one 64-lane block per row, lane = expert.
__global__ void gate_repair(const float* __restrict__ x, const float* __restrict__ W,
                            const float* __restrict__ b, const float* __restrict__ noise,
                            float* __restrict__ out, const unsigned int* __restrict__ flags,
                            int D) {
    unsigned int cnt = flags[0];
    if (cnt > CAP) cnt = CAP;
    if (blockIdx.x >= cnt) return;
    const int r = (int)flags[1 + blockIdx.x];
    const int e = threadIdx.x;  // 0..63

    const float* xr = x + (size_t)r * D;
    const float* wr = W + (size_t)e * D;
    double s = 0.0;
    for (int d0 = 0; d0 < D; d0 += 4) {
        float4 xv = *(const float4*)(xr + d0);
        float4 wv = *(const float4*)(wr + d0);
        s += (double)xv.x * (double)wv.x;
        s += (double)xv.y * (double)wv.y;
        s += (double)xv.z * (double)wv.z;
        s += (double)xv.w * (double)wv.w;
    }
    const float clean = (float)s + b[e];
    const float v     = clean + noise[(size_t)r * NEXP + e];

    float v1 = v, v2 = -1e30f; int e1 = e, e2 = 99;
    for (int d = 1; d < 64; d <<= 1) {
        float ov1 = __shfl_xor(v1, d); int oe1 = __shfl_xor(e1, d);
        float ov2 = __shfl_xor(v2, d); int oe2 = __shfl_xor(e2, d);
        bool  aw  = beats(v1, e1, ov1, oe1);
        float a1v = aw ? v1 : ov1; int a1e = aw ? e1 : oe1;
        float b1v = aw ? ov1 : v1; int b1e = aw ? oe1 : e1;
        float a2v = aw ? v2 : ov2; int a2e = aw ? e2 : oe2;
        bool  s2  = beats(a2v, a2e, b1v, b1e);
        v1 = a1v; e1 = a1e;
        v2 = s2 ? a2v : b1v; e2 = s2 ? a2e : b1e;
    }
    const float t   = __expf(v2 - v1);
    const float inv = 1.0f / (1.0f + t);
    out[(size_t)r * NEXP + e] = (e == e1) ? inv : (e == e2) ? t * inv : 0.0f;
}

extern "C" void kernel_launch(void* const* d_in, const int* in_sizes, int n_in,
                              void* d_out, int out_size, void* d_ws, size_t ws_size,
                              hipStream_t stream) {
    const float* x     = (const float*)d_in[0];
    const float* W     = (const float*)d_in[1];
    const float* b     = (const float*)d_in[2];
    const float* noise = (const float*)d_in[3];
    float* out = (float*)d_out;

    const int E = in_sizes[2];       // 64
    const int D = in_sizes[1] / E;   // 1024
    const int N = in_sizes[0] / D;   // 131072

    unsigned int* flags = (unsigned int*)d_ws;
    char* wsW = (char*)d_ws + WS_W_OFF;

    convW_kernel<<<dim3(E), dim3(128), 0, stream>>>(W, wsW);
    hipMemsetAsync(d_ws, 0, sizeof(unsigned int), stream);
    gate_mfma<<<dim3(N / TILE_M), dim3(BLOCK), 0, stream>>>(x, b, noise, wsW, out, flags);
    gate_repair<<<dim3(CAP), dim3(64), 0, stream>>>(x, W, b, noise, out, flags, D);
}